// Round 2
// baseline (115.638 us; speedup 1.0000x reference)
//
#include <hip/hip_runtime.h>

// NCC loss: 9x9 box-filtered local cross-correlation, -mean(cc).
// Inputs: y_pred, y_true (32,4,512,512) fp32. Output: scalar fp32.
//
// R2: TPB 128->256 (CPT=2), double-buffered LDS -> 1 barrier/iter.
// Goal: lift occupancy cap 50% -> 87.5% (7 blocks/CU, 20.8KB LDS each).

#define PAD 4
#define EPS 1e-5f

constexpr int B = 32, C = 4, H = 512, W = 512;
constexpr int ROWS = 32;             // output rows per block
constexpr int TPB = 256;             // threads per block (4 waves)
constexpr int CPT = 2;               // columns per thread (256*2 = 512 = W)
constexpr int SLOTS = 520;           // 4 halo + 512 + 4 halo
constexpr int NCHUNK = H / ROWS;     // 16
constexpr int NBLK = B * C * NCHUNK; // 2048
constexpr int NPART = NBLK * 4;      // one partial per wave
constexpr float INV_N = 1.0f / 81.0f;

template <bool ADD>
__device__ __forceinline__ void accrow(const float* __restrict__ I,
                                       const float* __restrict__ J,
                                       int r, int x0, float s[5][CPT]) {
    const float2 vi = *(const float2*)(I + (size_t)r * W + x0);
    const float2 vj = *(const float2*)(J + (size_t)r * W + x0);
    float fi[CPT] = {vi.x, vi.y};
    float fj[CPT] = {vj.x, vj.y};
#pragma unroll
    for (int k = 0; k < CPT; ++k) {
        float a = fi[k], b = fj[k];
        if (ADD) {
            s[0][k] += a; s[1][k] += b;
            s[2][k] += a * a; s[3][k] += b * b; s[4][k] += a * b;
        } else {
            s[0][k] -= a; s[1][k] -= b;
            s[2][k] -= a * a; s[3][k] -= b * b; s[4][k] -= a * b;
        }
    }
}

__global__ __launch_bounds__(TPB) void ncc_partial(
        const float* __restrict__ y_pred, const float* __restrict__ y_true,
        float* __restrict__ partial) {
    // Double-buffered vertical-sum rows: 2 * 5 * 520 * 4B = 20800 B.
    __shared__ float vs[2][5][SLOTS];

    const int bid = blockIdx.x;
    const int chunk = bid % NCHUNK;
    const int plane = bid / NCHUNK;
    const size_t base = (size_t)plane * H * W;
    const float* I = y_true + base;  // reference: I = y_true
    const float* J = y_pred + base;  // reference: J = y_pred

    const int t = threadIdx.x;
    const int x0 = t * CPT;  // this thread's 2 output columns

    // Zero the halo slots once in BOTH buffers (SAME zero-padding).
    if (t < 2 * PAD) {
        const int sl = (t < PAD) ? t : (512 + t);  // 0..3 and 516..519
#pragma unroll
        for (int b = 0; b < 2; ++b)
#pragma unroll
            for (int ch = 0; ch < 5; ++ch) vs[b][ch][sl] = 0.0f;
    }

    const int y0 = chunk * ROWS;

    // Running vertical sums over rows [y-4, y+4], 5 moment channels x 2 cols.
    float s[5][CPT] = {{0.f, 0.f}, {0.f, 0.f}, {0.f, 0.f}, {0.f, 0.f}, {0.f, 0.f}};

    // Prime with rows [y0-4, y0+3] ∩ [0,H)
    for (int r = y0 - PAD; r < y0 + PAD; ++r) {
        if (r >= 0 && r < H) accrow<true>(I, J, r, x0, s);
    }

    float acc = 0.0f;

    for (int yo = 0; yo < ROWS; ++yo) {
        const int y = y0 + yo;
        const int rin = y + PAD;
        if (rin < H) accrow<true>(I, J, rin, x0, s);
        // s now covers rows [y-4, y+4] (zero outside image)

        float (* const vb)[SLOTS] = vs[yo & 1];
#pragma unroll
        for (int ch = 0; ch < 5; ++ch)
            *(float2*)&vb[ch][x0 + PAD] = make_float2(s[ch][0], s[ch][1]);
        __syncthreads();
        // Single barrier per iter: buffer written this iter is read this
        // iter; the other buffer's readers were fenced by the PREVIOUS
        // iteration's barrier before anyone can overwrite it next iter.

        // Horizontal 9-sum: output col x window = slots [x, x+8] (slot=col+PAD).
        float h[5][CPT];
#pragma unroll
        for (int ch = 0; ch < 5; ++ch) {
            const float* row = vb[ch];
            const float2 r0 = *(const float2*)(row + x0);
            const float2 r1 = *(const float2*)(row + x0 + 2);
            const float2 r2 = *(const float2*)(row + x0 + 4);
            const float2 r3 = *(const float2*)(row + x0 + 6);
            const float2 r4 = *(const float2*)(row + x0 + 8);
            const float s0 = r0.x + r0.y + r1.x + r1.y + r2.x + r2.y +
                             r3.x + r3.y + r4.x;
            h[ch][0] = s0;
            h[ch][1] = s0 + r4.y - r0.x;
        }

#pragma unroll
        for (int k = 0; k < CPT; ++k) {
            const float mI = h[0][k] * INV_N;
            const float mJ = h[1][k] * INV_N;
            const float vI = h[2][k] * INV_N - mI * mI;
            const float vJ = h[3][k] * INV_N - mJ * mJ;
            const float cv = h[4][k] * INV_N - mI * mJ;
            const float den = fmaxf(vI, 0.0f) * fmaxf(vJ, 0.0f) + EPS;
            acc += cv * cv / den;
        }

        const int rout = y - PAD;
        if (rout >= 0) accrow<false>(I, J, rout, x0, s);
    }

    // Per-wave reduction, one partial per wave (no LDS, no extra barrier).
#pragma unroll
    for (int off = 32; off > 0; off >>= 1)
        acc += __shfl_down(acc, off, 64);
    if ((t & 63) == 0) partial[bid * 4 + (t >> 6)] = acc;
}

__global__ __launch_bounds__(256) void ncc_final(
        const float* __restrict__ partial, float* __restrict__ out) {
    const int t = threadIdx.x;
    float sum = 0.0f;
    for (int i = t; i < NPART; i += 256) sum += partial[i];
    __shared__ float ws[4];
#pragma unroll
    for (int off = 32; off > 0; off >>= 1)
        sum += __shfl_down(sum, off, 64);
    if ((t & 63) == 0) ws[t >> 6] = sum;
    __syncthreads();
    if (t == 0) {
        const float tot = ws[0] + ws[1] + ws[2] + ws[3];
        out[0] = -tot / (float)((long long)B * C * H * W);
    }
}

extern "C" void kernel_launch(void* const* d_in, const int* in_sizes, int n_in,
                              void* d_out, int out_size, void* d_ws, size_t ws_size,
                              hipStream_t stream) {
    const float* y_pred = (const float*)d_in[0];
    const float* y_true = (const float*)d_in[1];
    float* out = (float*)d_out;
    float* partial = (float*)d_ws;  // NPART floats = 32 KB

    ncc_partial<<<NBLK, TPB, 0, stream>>>(y_pred, y_true, partial);
    ncc_final<<<1, 256, 0, stream>>>(partial, out);
}